// Round 3
// baseline (293.769 us; speedup 1.0000x reference)
//
#include <hip/hip_runtime.h>

typedef __bf16 bf16;
typedef __bf16 bf16x8 __attribute__((ext_vector_type(8)));
typedef float f32x4 __attribute__((ext_vector_type(4)));

#define B_ 128
#define T_ 200
#define V_ 50257
#define H_ 256
#define E_ 128
#define OOV_ 50
#define VO_ 50307          // V + OOV
#define PSTR 3144          // pg_part row stride
#define NBG 112            // n-rows per k_score_g block
#define NTB 7              // 16-wide n-tiles per block
#define GBG 449            // grid for k_score_g (449*112 = 50288 >= V)
#define TILES_G 3143       // 449*7 written tiles

__device__ __forceinline__ float sigmoid_(float x) { return 1.0f / (1.0f + __expf(-x)); }
__device__ __forceinline__ float tanh_(float x) { return 1.0f - 2.0f / (__expf(2.0f * x) + 1.0f); }

// K0: pack Wc fp32 [256 n][512 k] -> bf16 frag order [nt(16)][kstep(16)][lane(64)][8]
// linear coalesced float4 reads; scattered 8B writes (tiny kernel, 256KB total)
__global__ void k_cvt_wc(const float* Wc_w, bf16* WcPack) {
    int gid = blockIdx.x * 256 + threadIdx.x;   // 32768 float4s
    int n = gid >> 7;
    int k4 = gid & 127;
    int k = k4 * 4;
    float4 v = *(const float4*)(Wc_w + n * 512 + k);
    int kstep = k >> 5, kin = k & 31;
    int q = kin >> 3, j0 = kin & 7;             // j0 in {0,4}
    int r = n & 15, nt = n >> 4;
    int lane = q * 16 + r;
    bf16* d = WcPack + (((nt * 16 + kstep) * 64) + lane) * 8 + j0;
    d[0] = (bf16)v.x; d[1] = (bf16)v.y; d[2] = (bf16)v.z; d[3] = (bf16)v.w;
}

// K1: resolve step, build h_prev^T and gru_in^T (transposed for coalesced GEMM reads)
__global__ void k_prep(const int* step_p, const float* enc, const float* prev,
                       const float* selread, const int* dec, const float* emb,
                       const float* Wi_w, const float* Wi_b,
                       float* hT, float* ginT) {
    int b = blockIdx.x, t = threadIdx.x;
    int step = step_p[0];
    float h;
    if (step == 0) {
        float acc = Wi_b[t];
        const float* er = enc + (b * T_ + (T_ - 1)) * 512;
        const float* wr = Wi_w + t * 512;
        for (int k = 0; k < 512; ++k) acc += er[k] * wr[k];
        h = acc;
    } else {
        h = prev[b * H_ + t];
    }
    hT[t * B_ + b] = h;
    for (int k = t; k < 512; k += 256)
        ginT[k * B_ + b] = (step == 0) ? 0.0f : selread[b * 512 + k];
    if (t < E_)
        ginT[(512 + t) * B_ + b] = emb[dec[b] * E_ + t];
}

// K2: gi = gru_in @ W_ih^T + b_ih ; gh = h @ W_hh^T + b_hh  (fp32)
__global__ void k_gemm_gru(const float* W_ih, const float* b_ih,
                           const float* W_hh, const float* b_hh,
                           const float* ginT, const float* hT,
                           float* giT, float* ghT) {
    int g = blockIdx.x * 256 + threadIdx.x;
    int r = g >> 7, b = g & 127;
    float acc = b_ih[r];
    const float* w = W_ih + r * 640;
#pragma unroll 8
    for (int k = 0; k < 640; ++k) acc += w[k] * ginT[k * B_ + b];
    giT[r * B_ + b] = acc;
    float acc2 = b_hh[r];
    const float* w2 = W_hh + r * 256;
#pragma unroll 8
    for (int k = 0; k < 256; ++k) acc2 += w2[k] * hT[k * B_ + b];
    ghT[r * B_ + b] = acc2;
}

// K3: GRU cell -> decode_hidden fp32 (out) + bf16 A-fragment-packed copy
__global__ void k_gru_cell(const float* giT, const float* ghT, const float* hT,
                           float* out_dh, bf16* Apack) {
    int b = blockIdx.x, j = threadIdx.x;
    float ir = giT[j * B_ + b], iz = giT[(256 + j) * B_ + b], in_ = giT[(512 + j) * B_ + b];
    float hr = ghT[j * B_ + b], hz = ghT[(256 + j) * B_ + b], hn = ghT[(512 + j) * B_ + b];
    float hp = hT[j * B_ + b];
    float r = sigmoid_(ir + hr);
    float z = sigmoid_(iz + hz);
    float n = tanh_(in_ + r * hn);
    float h = (1.0f - z) * n + z * hp;
    out_dh[b * H_ + j] = h;
    // Apack[mt(8)][ks(8)][lane(64)][8]: m = mt*16 + (lane&15), k = ks*32 + (lane>>4)*8 + jj
    int mt = b >> 4, rr = b & 15, ks = j >> 5, q = (j >> 3) & 3, jj = j & 7;
    Apack[(((mt * 8 + ks) * 64) + (q * 16 + rr)) * 8 + jj] = (bf16)h;
}

// K4: score_g. Block = 112 n-rows; wave holds 2 m-tiles of A in regs (16 frags);
// Wg staged once into LDS (coalesced row bursts); inner loop = ds_read + MFMA only.
__global__ __launch_bounds__(256, 2) void k_score_g(const bf16* Apack, const float* Wg_w,
                                                    const float* Wg_b, float* out_prob,
                                                    float* pg_part) {
    __shared__ bf16 Bs[NBG * 264];   // 112 rows x 256 k, stride 264 (59136 B)
    int tid = threadIdx.x;
    int blk = blockIdx.x;
    int n0 = blk * NBG;
    // stage: one full 1KB row per wave-instruction, 28 rounds
#pragma unroll
    for (int j = 0; j < 28; ++j) {
        int f = tid + j * 256;       // float4 id; 64 float4 per row
        int row = f >> 6;
        int c4 = f & 63;
        int n = n0 + row;
        float4 v = (n < V_) ? *(const float4*)(Wg_w + n * 256 + c4 * 4)
                            : float4{0.f, 0.f, 0.f, 0.f};
        bf16* d = Bs + row * 264 + c4 * 4;
        d[0] = (bf16)v.x; d[1] = (bf16)v.y; d[2] = (bf16)v.z; d[3] = (bf16)v.w;
    }
    int w = tid >> 6, lane = tid & 63;
    int r = lane & 15, q = lane >> 4;
    // A fragments: 2 m-tiles x 8 k-steps, loaded once from L2-hot Apack
    bf16x8 a[2][8];
#pragma unroll
    for (int p = 0; p < 2; ++p)
#pragma unroll
        for (int ks = 0; ks < 8; ++ks)
            a[p][ks] = *(const bf16x8*)(Apack + (((2 * w + p) * 8 + ks) * 64 + lane) * 8);
    __syncthreads();
    f32x4 acc[14];
#pragma unroll
    for (int i = 0; i < 14; ++i) acc[i] = (f32x4){0.f, 0.f, 0.f, 0.f};
#pragma unroll
    for (int ks = 0; ks < 8; ++ks) {
#pragma unroll
        for (int nt = 0; nt < NTB; ++nt) {
            bf16x8 bfr = *(const bf16x8*)(Bs + (nt * 16 + r) * 264 + ks * 32 + q * 8);
            acc[nt * 2]     = __builtin_amdgcn_mfma_f32_16x16x32_bf16(a[0][ks], bfr, acc[nt * 2], 0, 0, 0);
            acc[nt * 2 + 1] = __builtin_amdgcn_mfma_f32_16x16x32_bf16(a[1][ks], bfr, acc[nt * 2 + 1], 0, 0, 0);
        }
    }
#pragma unroll
    for (int nt = 0; nt < NTB; ++nt) {
        int n = n0 + nt * 16 + r;
        bool valid = n < V_;
        float wgb = valid ? Wg_b[n] : 0.0f;
#pragma unroll
        for (int p = 0; p < 2; ++p) {
#pragma unroll
            for (int rg = 0; rg < 4; ++rg) {
                int row = (2 * w + p) * 16 + q * 4 + rg;
                float e = valid ? __expf(acc[nt * 2 + p][rg] + wgb) : 0.0f;
                if (valid) out_prob[row * VO_ + n] = e;
                float sred = e;
                sred += __shfl_xor(sred, 1);
                sred += __shfl_xor(sred, 2);
                sred += __shfl_xor(sred, 4);
                sred += __shfl_xor(sred, 8);
                if (r == 0) pg_part[row * PSTR + blk * NTB + nt] = sred;
            }
        }
    }
}

// K5: fused enc_proj + score_c. Wave owns 4 n-tiles x 4 m-tiles; B-frags read
// directly from frag-packed global (L2); A staged in two LDS half-K chunks.
__global__ __launch_bounds__(256) void k_proj_c(const float* enc, const bf16* WcPack,
                                                const float* Wc_b, const float* dh,
                                                const int* idxs, float* expc) {
    __shared__ bf16 As[64 * 264];    // 64 m-rows x 256 k (one half), 33792 B
    __shared__ float sred[64 * 4];
    int tid = threadIdx.x;
    int m0 = blockIdx.x * 64;
    int w = tid >> 6, lane = tid & 63;
    int r = lane & 15, q = lane >> 4;
    f32x4 acc[16];
#pragma unroll
    for (int i = 0; i < 16; ++i) acc[i] = (f32x4){0.f, 0.f, 0.f, 0.f};
    for (int half = 0; half < 2; ++half) {
        __syncthreads();
        // stage 64 rows x 256 cols fp32 -> bf16 (one full row per wave-instr)
#pragma unroll
        for (int j = 0; j < 16; ++j) {
            int f = tid + j * 256;
            int row = f >> 6;
            int c4 = f & 63;
            float4 v = *(const float4*)(enc + (m0 + row) * 512 + half * 256 + c4 * 4);
            bf16* d = As + row * 264 + c4 * 4;
            d[0] = (bf16)v.x; d[1] = (bf16)v.y; d[2] = (bf16)v.z; d[3] = (bf16)v.w;
        }
        __syncthreads();
#pragma unroll
        for (int ks = 0; ks < 8; ++ks) {
            int kstep = half * 8 + ks;
            bf16x8 bfr[4];
#pragma unroll
            for (int ntl = 0; ntl < 4; ++ntl)
                bfr[ntl] = *(const bf16x8*)(WcPack + (((w * 4 + ntl) * 16 + kstep) * 64 + lane) * 8);
#pragma unroll
            for (int mt = 0; mt < 4; ++mt) {
                bf16x8 a = *(const bf16x8*)(As + (mt * 16 + r) * 264 + ks * 32 + q * 8);
#pragma unroll
                for (int ntl = 0; ntl < 4; ++ntl)
                    acc[mt * 4 + ntl] = __builtin_amdgcn_mfma_f32_16x16x32_bf16(a, bfr[ntl], acc[mt * 4 + ntl], 0, 0, 0);
            }
        }
    }
    // epilogue: pv = tanh(acc + bias); partial s = sum_n pv*dh; cross-wave reduce in LDS
#pragma unroll
    for (int mt = 0; mt < 4; ++mt) {
#pragma unroll
        for (int rg = 0; rg < 4; ++rg) {
            int rowl = mt * 16 + q * 4 + rg;
            int row = m0 + rowl;
            int b = row / T_;
            float s = 0.0f;
#pragma unroll
            for (int ntl = 0; ntl < 4; ++ntl) {
                int n = (w * 4 + ntl) * 16 + r;
                float pv = tanh_(acc[mt * 4 + ntl][rg] + Wc_b[n]);
                s += pv * dh[b * H_ + n];
            }
            s += __shfl_xor(s, 1);
            s += __shfl_xor(s, 2);
            s += __shfl_xor(s, 4);
            s += __shfl_xor(s, 8);
            if (r == 0) sred[rowl * 4 + w] = s;
        }
    }
    __syncthreads();
    if (tid < 64) {
        float s = sred[tid * 4] + sred[tid * 4 + 1] + sred[tid * 4 + 2] + sred[tid * 4 + 3];
        int row = m0 + tid;
        int b = row / T_, t = row - b * T_;
        float sc = tanh_(s);
        if (idxs[b * T_ + t] == 0) sc -= 10000.0f;
        expc[row] = __expf(sc);
    }
}

// K6: inv[b] = 1 / (sum_tiles pg_part + sum_t expc)
__global__ void k_rowsum(const float* pg_part, const float* expc, float* inv) {
    __shared__ float red[256];
    int b = blockIdx.x, t = threadIdx.x;
    float s = 0.0f;
    for (int nt = t; nt < TILES_G; nt += 256) s += pg_part[b * PSTR + nt];
    if (t < T_) s += expc[b * T_ + t];
    red[t] = s;
    __syncthreads();
    for (int k = 128; k > 0; k >>= 1) {
        if (t < k) red[t] += red[t + k];
        __syncthreads();
    }
    if (t == 0) inv[b] = 1.0f / red[0];
}

// K7: normalize expg in place, fill OOV/tail pad with 1e-4
__global__ void k_norm(float* out_prob, const float* inv) {
    int i4 = blockIdx.x * 256 + threadIdx.x;
    if (i4 >= (B_ * VO_ / 4)) return;
    float4 vv = ((const float4*)out_prob)[i4];
    float r[4];
    int base = i4 * 4;
#pragma unroll
    for (int c = 0; c < 4; ++c) {
        int idx = base + c;
        int b = idx / VO_;
        int v = idx - b * VO_;
        float x = (c == 0) ? vv.x : (c == 1) ? vv.y : (c == 2) ? vv.z : vv.w;
        r[c] = (v < V_) ? x * inv[b] : 1e-4f;
    }
    ((float4*)out_prob)[i4] = make_float4(r[0], r[1], r[2], r[3]);
}

// K8: scatter prob_c into out_prob; selective_read_new
__global__ void k_scatter_sel(const float* expc, const float* inv, const int* idxs,
                              const int* dec, const float* enc,
                              float* out_prob, float* out_sel) {
    __shared__ float cf[256];
    __shared__ float red[256];
    int b = blockIdx.x, t = threadIdx.x;
    int d = dec[b];
    float iv = inv[b];
    float pc = 0.0f;
    int m = 0;
    if (t < T_) {
        int ix = idxs[b * T_ + t];
        pc = expc[b * T_ + t] * iv;
        atomicAdd(&out_prob[b * VO_ + ix], pc);
        m = (ix == d) ? 1 : 0;
    }
    cf[t] = m ? pc : 0.0f;
    red[t] = m ? 1.0f : 0.0f;
    __syncthreads();
    for (int s = 128; s > 0; s >>= 1) {
        if (t < s) red[t] += red[t + s];
        __syncthreads();
    }
    float tot = red[0];
    float scale = (tot > 1.0f) ? 1.0f / tot : 1.0f;
    float a0 = 0.0f, a1 = 0.0f;
    for (int tt = 0; tt < T_; ++tt) {
        float c = cf[tt];
        if (c != 0.0f) {
            float w = c * scale;
            a0 += w * enc[(b * T_ + tt) * 512 + t];
            a1 += w * enc[(b * T_ + tt) * 512 + t + 256];
        }
    }
    out_sel[b * 512 + t] = a0;
    out_sel[b * 512 + t + 256] = a1;
}

extern "C" void kernel_launch(void* const* d_in, const int* in_sizes, int n_in,
                              void* d_out, int out_size, void* d_ws, size_t ws_size,
                              hipStream_t stream) {
    const int*   dec     = (const int*)d_in[0];
    const float* enc     = (const float*)d_in[1];
    const int*   idxs    = (const int*)d_in[2];
    const float* prev    = (const float*)d_in[3];
    const float* selread = (const float*)d_in[4];
    const int*   step_p  = (const int*)d_in[5];
    const float* emb     = (const float*)d_in[6];
    const float* W_ih    = (const float*)d_in[7];
    const float* W_hh    = (const float*)d_in[8];
    const float* b_ih    = (const float*)d_in[9];
    const float* b_hh    = (const float*)d_in[10];
    const float* Wi_w    = (const float*)d_in[11];
    const float* Wi_b    = (const float*)d_in[12];
    const float* Wg_w    = (const float*)d_in[13];
    const float* Wg_b    = (const float*)d_in[14];
    const float* Wc_w    = (const float*)d_in[15];
    const float* Wc_b    = (const float*)d_in[16];

    float* ws     = (float*)d_ws;
    float* hT     = ws;                 // 32768
    float* ginT   = ws + 32768;         // 81920
    float* giT    = ws + 114688;        // 98304
    float* ghT    = ws + 212992;        // 98304
    float* inv    = ws + 311296;        // 128
    float* expc   = ws + 311552;        // 25600
    float* pgp    = ws + 337152;        // 128*3144 = 402432
    bf16*  Apack  = (bf16*)(ws + 739584);   // 32768 bf16 (64KB)
    bf16*  WcPack = (bf16*)(ws + 755968);   // 131072 bf16 (256KB)

    float* out      = (float*)d_out;
    float* out_prob = out;                       // 128*50307
    float* out_dh   = out + 6439296;             // 128*256
    float* out_sel  = out + 6439296 + 32768;     // 128*512

    k_cvt_wc<<<128, 256, 0, stream>>>(Wc_w, WcPack);
    k_prep<<<B_, 256, 0, stream>>>(step_p, enc, prev, selread, dec, emb, Wi_w, Wi_b, hT, ginT);
    k_gemm_gru<<<384, 256, 0, stream>>>(W_ih, b_ih, W_hh, b_hh, ginT, hT, giT, ghT);
    k_gru_cell<<<B_, 256, 0, stream>>>(giT, ghT, hT, out_dh, Apack);
    k_score_g<<<GBG, 256, 0, stream>>>(Apack, Wg_w, Wg_b, out_prob, pgp);
    k_proj_c<<<400, 256, 0, stream>>>(enc, WcPack, Wc_b, out_dh, idxs, expc);
    k_rowsum<<<B_, 256, 0, stream>>>(pgp, expc, inv);
    k_norm<<<(B_ * VO_ / 4 + 255) / 256, 256, 0, stream>>>(out_prob, inv);
    k_scatter_sel<<<B_, 256, 0, stream>>>(expc, inv, idxs, dec, enc, out_prob, out_sel);
}

// Round 4
// 271.311 us; speedup vs baseline: 1.0828x; 1.0828x over previous
//
#include <hip/hip_runtime.h>

typedef __bf16 bf16;
typedef __bf16 bf16x8 __attribute__((ext_vector_type(8)));
typedef float f32x4 __attribute__((ext_vector_type(4)));

#define B_ 128
#define T_ 200
#define V_ 50257
#define H_ 256
#define E_ 128
#define OOV_ 50
#define VO_ 50307          // V + OOV
#define NRG 80             // n-rows per score block
#define NTS 5              // 16-wide n-tiles per score block
#define GSC 629            // score blocks (629*80 = 50320 >= V)
#define TILES_G 3145       // 629*5 partial tiles
#define PSTR 3152          // pg_part row stride (padded)
#define GPJ 400            // proj blocks

__device__ __forceinline__ float sigmoid_(float x) { return 1.0f / (1.0f + __expf(-x)); }
__device__ __forceinline__ float tanh_(float x) { return 1.0f - 2.0f / (__expf(2.0f * x) + 1.0f); }

// K1: fused front kernel. blocks [0,128): pack Wc fp32 -> bf16 frag order
// [nt(16)][kstep(16)][lane(64)][8]; blocks [128,256): prep (hT, ginT).
__global__ void k_front(const float* Wc_w, bf16* WcPack,
                        const int* step_p, const float* enc, const float* prev,
                        const float* selread, const int* dec, const float* emb,
                        const float* Wi_w, const float* Wi_b,
                        float* hT, float* ginT) {
    if (blockIdx.x < 128) {
        int gid = blockIdx.x * 256 + threadIdx.x;   // 32768 float4s
        int n = gid >> 7;
        int k = (gid & 127) * 4;
        float4 v = *(const float4*)(Wc_w + n * 512 + k);
        int kstep = k >> 5, kin = k & 31;
        int q = kin >> 3, j0 = kin & 7;
        int r = n & 15, nt = n >> 4;
        int lane = q * 16 + r;
        bf16* d = WcPack + (((nt * 16 + kstep) * 64) + lane) * 8 + j0;
        d[0] = (bf16)v.x; d[1] = (bf16)v.y; d[2] = (bf16)v.z; d[3] = (bf16)v.w;
    } else {
        int b = blockIdx.x - 128, t = threadIdx.x;
        int step = step_p[0];
        float h;
        if (step == 0) {
            float acc = Wi_b[t];
            const float* er = enc + (b * T_ + (T_ - 1)) * 512;
            const float* wr = Wi_w + t * 512;
            for (int k = 0; k < 512; ++k) acc += er[k] * wr[k];
            h = acc;
        } else {
            h = prev[b * H_ + t];
        }
        hT[t * B_ + b] = h;
        for (int k = t; k < 512; k += 256)
            ginT[k * B_ + b] = (step == 0) ? 0.0f : selread[b * 512 + k];
        if (t < E_)
            ginT[(512 + t) * B_ + b] = emb[dec[b] * E_ + t];
    }
}

// K2: gi = gru_in @ W_ih^T + b_ih ; gh = h @ W_hh^T + b_hh  (fp32, 4-way ILP)
__global__ void k_gemm_gru(const float* W_ih, const float* b_ih,
                           const float* W_hh, const float* b_hh,
                           const float* ginT, const float* hT,
                           float* giT, float* ghT) {
    int g = blockIdx.x * 256 + threadIdx.x;
    int r = g >> 7, b = g & 127;
    const float* w = W_ih + r * 640;
    float a0 = 0.f, a1 = 0.f, a2 = 0.f, a3 = 0.f;
#pragma unroll 4
    for (int k = 0; k < 640; k += 4) {
        a0 += w[k]     * ginT[k * B_ + b];
        a1 += w[k + 1] * ginT[(k + 1) * B_ + b];
        a2 += w[k + 2] * ginT[(k + 2) * B_ + b];
        a3 += w[k + 3] * ginT[(k + 3) * B_ + b];
    }
    giT[r * B_ + b] = b_ih[r] + ((a0 + a1) + (a2 + a3));
    const float* w2 = W_hh + r * 256;
    float c0 = 0.f, c1 = 0.f, c2 = 0.f, c3 = 0.f;
#pragma unroll 4
    for (int k = 0; k < 256; k += 4) {
        c0 += w2[k]     * hT[k * B_ + b];
        c1 += w2[k + 1] * hT[(k + 1) * B_ + b];
        c2 += w2[k + 2] * hT[(k + 2) * B_ + b];
        c3 += w2[k + 3] * hT[(k + 3) * B_ + b];
    }
    ghT[r * B_ + b] = b_hh[r] + ((c0 + c1) + (c2 + c3));
}

// K3: GRU cell -> decode_hidden fp32 (out) + bf16 A-fragment-packed copy
__global__ void k_gru_cell(const float* giT, const float* ghT, const float* hT,
                           float* out_dh, bf16* Apack) {
    int b = blockIdx.x, j = threadIdx.x;
    float ir = giT[j * B_ + b], iz = giT[(256 + j) * B_ + b], in_ = giT[(512 + j) * B_ + b];
    float hr = ghT[j * B_ + b], hz = ghT[(256 + j) * B_ + b], hn = ghT[(512 + j) * B_ + b];
    float hp = hT[j * B_ + b];
    float r = sigmoid_(ir + hr);
    float z = sigmoid_(iz + hz);
    float n = tanh_(in_ + r * hn);
    float h = (1.0f - z) * n + z * hp;
    out_dh[b * H_ + j] = h;
    // Apack[mt(8)][ks(8)][lane(64)][8]: m = mt*16 + (lane&15), k = ks*32 + (lane>>4)*8 + jj
    int mt = b >> 4, rr = b & 15, ks = j >> 5, q = (j >> 3) & 3, jj = j & 7;
    Apack[(((mt * 8 + ks) * 64) + (q * 16 + rr)) * 8 + jj] = (bf16)h;
}

// K4: merged MFMA kernel. blocks [0,GSC): score_g; blocks [GSC,GSC+GPJ): proj+score_c.
__global__ __launch_bounds__(256, 3) void k_mm(const bf16* Apack, const float* Wg_w,
                                               const float* Wg_b, const float* enc,
                                               const bf16* WcPack, const float* Wc_b,
                                               const float* dh, const int* idxs,
                                               float* out_prob, float* pg_part, float* expc) {
    __shared__ unsigned char smem[43008];
    int tid = threadIdx.x;
    int w = tid >> 6, lane = tid & 63;
    int r = lane & 15, q = lane >> 4;
    if (blockIdx.x < GSC) {
        // ---------------- score_g path ----------------
        int blk = blockIdx.x;
        int n0 = blk * NRG;
        bf16* Bs = (bf16*)smem;          // 80 rows x 256 k, stride 264
        // two-phase deep-pipelined staging: 20 rounds = 2 x (10 loads, then 10 cvt+write)
#pragma unroll
        for (int ph = 0; ph < 2; ++ph) {
            float4 tmp[10];
#pragma unroll
            for (int j = 0; j < 10; ++j) {
                int f = (ph * 10 + j) * 256 + tid;
                int row = f >> 6, c4 = f & 63;
                int n = n0 + row;
                tmp[j] = (n < V_) ? *(const float4*)(Wg_w + n * 256 + c4 * 4)
                                  : float4{0.f, 0.f, 0.f, 0.f};
            }
#pragma unroll
            for (int j = 0; j < 10; ++j) {
                int f = (ph * 10 + j) * 256 + tid;
                int row = f >> 6, c4 = f & 63;
                bf16* d = Bs + row * 264 + c4 * 4;
                d[0] = (bf16)tmp[j].x; d[1] = (bf16)tmp[j].y;
                d[2] = (bf16)tmp[j].z; d[3] = (bf16)tmp[j].w;
            }
        }
        // A fragments loaded AFTER staging (registers free during staging)
        bf16x8 a[2][8];
#pragma unroll
        for (int p = 0; p < 2; ++p)
#pragma unroll
            for (int ks = 0; ks < 8; ++ks)
                a[p][ks] = *(const bf16x8*)(Apack + ((2 * w + p) * 8 + ks) * 512 + lane * 8);
        __syncthreads();
        f32x4 acc[10];
#pragma unroll
        for (int i = 0; i < 10; ++i) acc[i] = (f32x4){0.f, 0.f, 0.f, 0.f};
#pragma unroll
        for (int ks = 0; ks < 8; ++ks) {
#pragma unroll
            for (int nt = 0; nt < NTS; ++nt) {
                bf16x8 bfr = *(const bf16x8*)(Bs + (nt * 16 + r) * 264 + ks * 32 + q * 8);
                acc[nt * 2]     = __builtin_amdgcn_mfma_f32_16x16x32_bf16(a[0][ks], bfr, acc[nt * 2], 0, 0, 0);
                acc[nt * 2 + 1] = __builtin_amdgcn_mfma_f32_16x16x32_bf16(a[1][ks], bfr, acc[nt * 2 + 1], 0, 0, 0);
            }
        }
        __syncthreads();                 // Bs reads done; reuse smem as transpose buffer
        float* Tr = (float*)smem;        // 128 rows x 80, stride 84 (16B-aligned)
#pragma unroll
        for (int nt = 0; nt < NTS; ++nt) {
            int n = n0 + nt * 16 + r;
            bool valid = n < V_;
            float wgb = valid ? Wg_b[n] : 0.0f;
#pragma unroll
            for (int p = 0; p < 2; ++p) {
#pragma unroll
                for (int rg = 0; rg < 4; ++rg) {
                    int row = (2 * w + p) * 16 + q * 4 + rg;
                    float e = valid ? __expf(acc[nt * 2 + p][rg] + wgb) : 0.0f;
                    Tr[row * 84 + nt * 16 + r] = e;
                    float sred = e;
                    sred += __shfl_xor(sred, 1);
                    sred += __shfl_xor(sred, 2);
                    sred += __shfl_xor(sred, 4);
                    sred += __shfl_xor(sred, 8);
                    if (r == 0) pg_part[row * PSTR + blk * NTS + nt] = sred;
                }
            }
        }
        __syncthreads();
        // coalesced stores: 448B-contiguous run per row (20 float4)
        if (blk < GSC - 1) {
#pragma unroll
            for (int rnd = 0; rnd < 10; ++rnd) {
                int f = rnd * 256 + tid;            // 2560 float4s
                int row = (f * 3277) >> 16;         // f / 20
                int c4 = f - row * 20;
                float4 v = *(const float4*)(Tr + row * 84 + c4 * 4);
                *(float4*)(out_prob + row * VO_ + n0 + c4 * 4) = v;
            }
        } else {
#pragma unroll
            for (int rnd = 0; rnd < 10; ++rnd) {
                int f = rnd * 256 + tid;
                int row = (f * 3277) >> 16;
                int c4 = f - row * 20;
#pragma unroll
                for (int i = 0; i < 4; ++i) {
                    int n = n0 + c4 * 4 + i;
                    if (n < V_) out_prob[row * VO_ + n] = Tr[row * 84 + c4 * 4 + i];
                }
            }
        }
    } else {
        // ---------------- proj + score_c path ----------------
        int pblk = blockIdx.x - GSC;
        int m0 = pblk * 64;
        bf16* As = (bf16*)smem;                    // 64 rows x 256 k, stride 264
        float* sred = (float*)(smem + 33792);      // 64 x 4
        f32x4 acc[16];
#pragma unroll
        for (int i = 0; i < 16; ++i) acc[i] = (f32x4){0.f, 0.f, 0.f, 0.f};
        for (int half = 0; half < 2; ++half) {
            __syncthreads();
            // two-phase staging: 16 rounds = 2 x (8 loads, 8 cvt+write)
#pragma unroll
            for (int ph = 0; ph < 2; ++ph) {
                float4 tmp[8];
#pragma unroll
                for (int j = 0; j < 8; ++j) {
                    int f = (ph * 8 + j) * 256 + tid;
                    int row = f >> 6, c4 = f & 63;
                    tmp[j] = *(const float4*)(enc + (m0 + row) * 512 + half * 256 + c4 * 4);
                }
#pragma unroll
                for (int j = 0; j < 8; ++j) {
                    int f = (ph * 8 + j) * 256 + tid;
                    int row = f >> 6, c4 = f & 63;
                    bf16* d = As + row * 264 + c4 * 4;
                    d[0] = (bf16)tmp[j].x; d[1] = (bf16)tmp[j].y;
                    d[2] = (bf16)tmp[j].z; d[3] = (bf16)tmp[j].w;
                }
            }
            __syncthreads();
#pragma unroll
            for (int ks = 0; ks < 8; ++ks) {
                int kstep = half * 8 + ks;
                bf16x8 bfr[4];
#pragma unroll
                for (int ntl = 0; ntl < 4; ++ntl)
                    bfr[ntl] = *(const bf16x8*)(WcPack + (((w * 4 + ntl) * 16 + kstep) * 64 + lane) * 8);
#pragma unroll
                for (int mt = 0; mt < 4; ++mt) {
                    bf16x8 a = *(const bf16x8*)(As + (mt * 16 + r) * 264 + ks * 32 + q * 8);
#pragma unroll
                    for (int ntl = 0; ntl < 4; ++ntl)
                        acc[mt * 4 + ntl] = __builtin_amdgcn_mfma_f32_16x16x32_bf16(a, bfr[ntl], acc[mt * 4 + ntl], 0, 0, 0);
                }
            }
        }
#pragma unroll
        for (int mt = 0; mt < 4; ++mt) {
#pragma unroll
            for (int rg = 0; rg < 4; ++rg) {
                int rowl = mt * 16 + q * 4 + rg;
                int row = m0 + rowl;
                int b = row / T_;
                float s = 0.0f;
#pragma unroll
                for (int ntl = 0; ntl < 4; ++ntl) {
                    int n = (w * 4 + ntl) * 16 + r;
                    float pv = tanh_(acc[mt * 4 + ntl][rg] + Wc_b[n]);
                    s += pv * dh[b * H_ + n];
                }
                s += __shfl_xor(s, 1);
                s += __shfl_xor(s, 2);
                s += __shfl_xor(s, 4);
                s += __shfl_xor(s, 8);
                if (r == 0) sred[rowl * 4 + w] = s;
            }
        }
        __syncthreads();
        if (tid < 64) {
            float s = sred[tid * 4] + sred[tid * 4 + 1] + sred[tid * 4 + 2] + sred[tid * 4 + 3];
            int row = m0 + tid;
            int b = row / T_, t = row - b * T_;
            float sc = tanh_(s);
            if (idxs[b * T_ + t] == 0) sc -= 10000.0f;
            expc[row] = __expf(sc);
        }
    }
}

// K5: per-b: inv = 1/(sum pg_part + sum expc); scatter RAW expc into out_prob
// (k_norm scales afterwards); selective_read with normalized pc.
__global__ void k_red_scatter(const float* pg_part, const float* expc_, const int* idxs,
                              const int* dec, const float* enc, float* inv_out,
                              float* out_prob, float* out_sel) {
    __shared__ float red[256];
    __shared__ float cf[256];
    int b = blockIdx.x, t = threadIdx.x;
    float s = 0.0f;
    for (int i = t; i < TILES_G; i += 256) s += pg_part[b * PSTR + i];
    if (t < T_) s += expc_[b * T_ + t];
    red[t] = s;
    __syncthreads();
    for (int k = 128; k > 0; k >>= 1) {
        if (t < k) red[t] += red[t + k];
        __syncthreads();
    }
    float iv = 1.0f / red[0];
    if (t == 0) inv_out[b] = iv;
    __syncthreads();
    int d = dec[b];
    float ec = 0.0f;
    int m = 0;
    if (t < T_) {
        int ix = idxs[b * T_ + t];
        ec = expc_[b * T_ + t];
        atomicAdd(&out_prob[b * VO_ + ix], ec);   // raw; k_norm multiplies by inv
        m = (ix == d) ? 1 : 0;
    }
    cf[t] = m ? ec * iv : 0.0f;
    red[t] = m ? 1.0f : 0.0f;
    __syncthreads();
    for (int k = 128; k > 0; k >>= 1) {
        if (t < k) red[t] += red[t + k];
        __syncthreads();
    }
    float tot = red[0];
    float scale = (tot > 1.0f) ? 1.0f / tot : 1.0f;
    float a0 = 0.0f, a1 = 0.0f;
    for (int tt = 0; tt < T_; ++tt) {
        float c = cf[tt];
        if (c != 0.0f) {
            float wgt = c * scale;
            a0 += wgt * enc[(b * T_ + tt) * 512 + t];
            a1 += wgt * enc[(b * T_ + tt) * 512 + t + 256];
        }
    }
    out_sel[b * 512 + t] = a0;
    out_sel[b * 512 + t + 256] = a1;
}

// K6: normalize out_prob in place (x inv), fill OOV pad with 1e-4
__global__ void k_norm(float* out_prob, const float* inv) {
    int i4 = blockIdx.x * 256 + threadIdx.x;
    if (i4 >= (B_ * VO_ / 4)) return;
    float4 vv = ((const float4*)out_prob)[i4];
    float r[4];
    int base = i4 * 4;
#pragma unroll
    for (int c = 0; c < 4; ++c) {
        int idx = base + c;
        int b = idx / VO_;
        int v = idx - b * VO_;
        float x = (c == 0) ? vv.x : (c == 1) ? vv.y : (c == 2) ? vv.z : vv.w;
        r[c] = (v < V_) ? x * inv[b] : 1e-4f;
    }
    ((float4*)out_prob)[i4] = make_float4(r[0], r[1], r[2], r[3]);
}

extern "C" void kernel_launch(void* const* d_in, const int* in_sizes, int n_in,
                              void* d_out, int out_size, void* d_ws, size_t ws_size,
                              hipStream_t stream) {
    const int*   dec     = (const int*)d_in[0];
    const float* enc     = (const float*)d_in[1];
    const int*   idxs    = (const int*)d_in[2];
    const float* prev    = (const float*)d_in[3];
    const float* selread = (const float*)d_in[4];
    const int*   step_p  = (const int*)d_in[5];
    const float* emb     = (const float*)d_in[6];
    const float* W_ih    = (const float*)d_in[7];
    const float* W_hh    = (const float*)d_in[8];
    const float* b_ih    = (const float*)d_in[9];
    const float* b_hh    = (const float*)d_in[10];
    const float* Wi_w    = (const float*)d_in[11];
    const float* Wi_b    = (const float*)d_in[12];
    const float* Wg_w    = (const float*)d_in[13];
    const float* Wg_b    = (const float*)d_in[14];
    const float* Wc_w    = (const float*)d_in[15];
    const float* Wc_b    = (const float*)d_in[16];

    float* ws     = (float*)d_ws;
    float* hT     = ws;                 // 32768
    float* ginT   = ws + 32768;         // 81920
    float* giT    = ws + 114688;        // 98304
    float* ghT    = ws + 212992;        // 98304
    float* inv    = ws + 311296;        // 128
    float* expc   = ws + 311552;        // 25600
    float* pgp    = ws + 337152;        // 128*3152 = 403456
    bf16*  Apack  = (bf16*)(ws + 741376);   // 32768 bf16 (64KB)
    bf16*  WcPack = (bf16*)(ws + 757760);   // 131072 bf16 (256KB)

    float* out      = (float*)d_out;
    float* out_prob = out;                       // 128*50307
    float* out_dh   = out + 6439296;             // 128*256
    float* out_sel  = out + 6439296 + 32768;     // 128*512

    k_front<<<256, 256, 0, stream>>>(Wc_w, WcPack, step_p, enc, prev, selread, dec,
                                     emb, Wi_w, Wi_b, hT, ginT);
    k_gemm_gru<<<384, 256, 0, stream>>>(W_ih, b_ih, W_hh, b_hh, ginT, hT, giT, ghT);
    k_gru_cell<<<B_, 256, 0, stream>>>(giT, ghT, hT, out_dh, Apack);
    k_mm<<<GSC + GPJ, 256, 0, stream>>>(Apack, Wg_w, Wg_b, enc, WcPack, Wc_b,
                                        out_dh, idxs, out_prob, pgp, expc);
    k_red_scatter<<<B_, 256, 0, stream>>>(pgp, expc, idxs, dec, enc, inv, out_prob, out_sel);
    k_norm<<<(B_ * VO_ / 4 + 255) / 256, 256, 0, stream>>>(out_prob, inv);
}